// Round 8
// baseline (849.225 us; speedup 1.0000x reference)
//
#include <hip/hip_runtime.h>
#include <hip/hip_bf16.h>

#define B_ 32
#define S_ 1024
#define D_ 512
#define P_ 20
#define G_ 80   // 4*P

typedef __attribute__((ext_vector_type(8))) short short8v;
typedef __attribute__((ext_vector_type(4))) float f32x4;

__device__ __forceinline__ float sigm_f(float x) { return 1.f / (1.f + __expf(-x)); }
__device__ __forceinline__ float tanh_f(float x) { return 1.f - 2.f / (__expf(2.f * x) + 1.f); }
__device__ __forceinline__ unsigned short f2bf(float f) {
    unsigned int u = __float_as_uint(f);
    u += 0x7FFF + ((u >> 16) & 1);   // RNE; inputs are finite
    return (unsigned short)(u >> 16);
}
__device__ __forceinline__ float bcast(float v, int lane) {
    return __uint_as_float(__builtin_amdgcn_readlane(__float_as_uint(v), lane));
}
// half-wave swap (lane i <-> lane i^32) via VALU permlane (no DS, no lgkmcnt)
__device__ __forceinline__ float swap32(float x, int l) {
    unsigned d = __float_as_uint(x);
    unsigned s = d;
    asm("v_permlane32_swap_b32 %0, %1" : "+v"(d), "+v"(s));
    return (l & 32) ? __uint_as_float(d) : __uint_as_float(s);
}
__device__ __forceinline__ short8v cvt8(float4 p, float4 q) {
    union { __hip_bfloat162 h2[4]; short8v s; } u;
    u.h2[0] = __float22bfloat162_rn(float2{p.x, p.y});
    u.h2[1] = __float22bfloat162_rn(float2{p.z, p.w});
    u.h2[2] = __float22bfloat162_rn(float2{q.x, q.y});
    u.h2[3] = __float22bfloat162_rn(float2{q.z, q.w});
    return u.s;
}

// ---------------- K1: xw = x @ W_ih^T + b_ih + b_hh  via MFMA bf16 ----------------
__global__ __launch_bounds__(256) void xw_kernel(const float* __restrict__ x,
                                                 const float* __restrict__ W_ih,
                                                 const float* __restrict__ b_ih,
                                                 const float* __restrict__ b_hh,
                                                 float* __restrict__ xw) {
    const int tid = threadIdx.x;
    const int w = tid >> 6, l = tid & 63;
    const int lo = l & 15, hi = l >> 4;
    const int m0 = blockIdx.x * 64 + w * 16;

    f32x4 acc[5];
#pragma unroll
    for (int n = 0; n < 5; ++n) acc[n] = (f32x4){0.f, 0.f, 0.f, 0.f};

    const float* xrow = x + (size_t)(m0 + lo) * D_ + hi * 8;
#pragma unroll 4
    for (int k0 = 0; k0 < D_; k0 += 32) {
        const float4 a0 = *(const float4*)(xrow + k0);
        const float4 a1 = *(const float4*)(xrow + k0 + 4);
        const short8v a = cvt8(a0, a1);
#pragma unroll
        for (int n = 0; n < 5; ++n) {
            const float* wr = W_ih + (size_t)(n * 16 + lo) * D_ + k0 + hi * 8;
            const float4 b0 = *(const float4*)(wr);
            const float4 b1 = *(const float4*)(wr + 4);
            const short8v bf = cvt8(b0, b1);
            acc[n] = __builtin_amdgcn_mfma_f32_16x16x32_bf16(a, bf, acc[n], 0, 0, 0);
        }
    }
#pragma unroll
    for (int n = 0; n < 5; ++n) {
        const int g = n * 16 + lo;
        const float bias = b_ih[g] + b_hh[g];
#pragma unroll
        for (int r = 0; r < 4; ++r) {
            const int m = m0 + hi * 4 + r;
            xw[(size_t)m * G_ + g] = acc[n][r] + bias;
        }
    }
}

// ---------------- K1b: transpose x -> xT[b][d][s] in bf16 ----------------
__global__ __launch_bounds__(256) void conv_kernel(const float* __restrict__ x,
                                                   unsigned short* __restrict__ xT) {
    __shared__ unsigned short tile[64][80];
    const int b = blockIdx.z;
    const int s0 = blockIdx.x * 64;
    const int d0 = blockIdx.y * 64;
    const int t = threadIdx.x;
    const int r = t >> 2;
    const int c0 = (t & 3) * 16;

    const float4* src = (const float4*)(x + ((size_t)(b * S_ + s0 + r)) * D_ + d0 + c0);
    float4 v0 = src[0], v1 = src[1], v2 = src[2], v3 = src[3];
    float vv[16] = {v0.x, v0.y, v0.z, v0.w, v1.x, v1.y, v1.z, v1.w,
                    v2.x, v2.y, v2.z, v2.w, v3.x, v3.y, v3.z, v3.w};
#pragma unroll
    for (int e = 0; e < 16; ++e) tile[c0 + e][r] = f2bf(vv[e]);
    __syncthreads();

    const int dr = t >> 2;
    const int sc = (t & 3) * 16;
    const unsigned short* tr = &tile[dr][sc];
    uint4 w0 = *(const uint4*)(tr);
    uint4 w1 = *(const uint4*)(tr + 8);
    uint4* dst = (uint4*)(xT + ((size_t)(b * D_ + d0 + dr)) * S_ + s0 + sc);
    dst[0] = w0;
    dst[1] = w1;
}

// ---------------- K2: split-gate LSTM, LDS-staged xw (NO global loads in the loop) ----------------
// lanes 0-19:  unit p=l, gates (i, f); lanes 32-51: unit p=l-32, gates (g, o)
// lanes 20-22: mu head rows; lane 23: sigma head.
// xw staged to LDS in 128-step chunks (bulk float4, one vmcnt drain per chunk);
// per-step operands come from a 4-deep ds_read ring -> vmcnt queue empty in loop.
__global__ __launch_bounds__(64) void lstm_kernel(const float* __restrict__ xw,
                                                  const float* __restrict__ W_hh,
                                                  const float* __restrict__ W_mu,
                                                  const float* __restrict__ b_mu,
                                                  const float* __restrict__ W_sig,
                                                  const float* __restrict__ b_sig,
                                                  const int* __restrict__ pad,
                                                  float* __restrict__ mus,
                                                  float* __restrict__ sigma) {
    const int b = blockIdx.x;
    const int l = threadIdx.x;
    __shared__ float mbuf[S_];
    __shared__ float sbuf[S_];
    __shared__ float stage[128 * G_];   // 40 KB: one 128-step chunk of xw

    float E[P_], F[P_];
#pragma unroll
    for (int q = 0; q < P_; ++q) { E[q] = 0.f; F[q] = 0.f; }
    if (l < P_) {
#pragma unroll
        for (int q = 0; q < P_; ++q) {
            E[q] = W_hh[(0 * P_ + l) * P_ + q];   // i row
            F[q] = W_hh[(1 * P_ + l) * P_ + q];   // f row
        }
    } else if (l < 23) {
#pragma unroll
        for (int q = 0; q < P_; ++q) E[q] = W_mu[(l - 20) * P_ + q];
    } else if (l == 23) {
#pragma unroll
        for (int q = 0; q < P_; ++q) E[q] = W_sig[q];
    } else if (l >= 32 && l < 32 + P_) {
        const int p = l - 32;
#pragma unroll
        for (int q = 0; q < P_; ++q) {
            E[q] = W_hh[(2 * P_ + p) * P_ + q];   // g row
            F[q] = W_hh[(3 * P_ + p) * P_ + q];   // o row
        }
    }

    const float invL = 1.f / (float)pad[b];
    const float hb = (l >= 20 && l < 23) ? b_mu[l - 20] : (l == 23 ? b_sig[0] : 0.f);
    const float ka = (l >= 32) ? 2.f : 1.f;
    const float Ka = (l >= 32) ? 2.f : 1.f;
    const float Kb = (l >= 32) ? -1.f : 0.f;
    const bool ld = (l < P_) || (l >= 32 && l < 32 + P_);
    const int o1 = (l < 32) ? l : (2 * P_ + (l - 32));          // i or g column
    const int o2 = (l < 32) ? (P_ + l) : (3 * P_ + (l - 32));   // f or o column

    float h = 0.f, c = 0.f, mu_prev = 0.f;
    const float4* xwb4 = (const float4*)(xw + (size_t)b * S_ * G_);

    float ri[4], rf[4];
#pragma unroll
    for (int u = 0; u < 4; ++u) { ri[u] = 0.f; rf[u] = 0.f; }

    // one LSTM step. u: ring slot (compile-time), rrow: LDS row to refill from (<0: none)
    auto STEP = [&](int t, int u, int rrow) {
        float hq[P_];
#pragma unroll
        for (int q = 0; q < P_; ++q) hq[q] = bcast(h, q);

        float pa = 0.f, pb = 0.f, pc = 0.f, pd = 0.f;
        float qa = 0.f, qb = 0.f, qc = 0.f, qd = 0.f;
#pragma unroll
        for (int q = 0; q < 5; ++q) {
            pa += E[q]      * hq[q];       qa += F[q]      * hq[q];
            pb += E[q + 5]  * hq[q + 5];   qb += F[q + 5]  * hq[q + 5];
            pc += E[q + 10] * hq[q + 10];  qc += F[q + 10] * hq[q + 10];
            pd += E[q + 15] * hq[q + 15];  qd += F[q + 15] * hq[q + 15];
        }
        const float arg1 = ((pa + pb) + (pc + pd)) + ri[u] + hb;
        const float arg2 = ((qa + qb) + (qc + qd)) + rf[u];

        const float s1 = sigm_f(ka * arg1);
        const float a1 = Ka * s1 + Kb;          // sigm (lo) / tanh (hi)
        const float a2 = sigm_f(arg2);
        const float rv = fmaxf(arg1, 0.f);      // relu for mu head lanes

        const float gx = swap32(a1, l);         // partner's a1
        const float ox = swap32(a2, l);         // partner's a2

        c = a2 * c + a1 * gx;
        h = ox * tanh_f(c);

        if (rrow >= 0 && ld) {                  // refill slot u from LDS
            ri[u] = stage[rrow * G_ + o1];
            rf[u] = stage[rrow * G_ + o2];
        }
        if (t > 0) {
            const float s0v = bcast(rv, 20);
            const float s1v = bcast(rv, 21);
            const float s2v = bcast(rv, 22);
            const float j = (float)(t - 1);
            float m = s0v * mu_prev + (s1v + s2v * (j + 1.f)) * invL;
            m = fmaxf(m, j * invL);
            mu_prev = m;
            if (l == 0) mbuf[t - 1] = m;
            if (l == 23) sbuf[t - 1] = s1;
        }
    };

    for (int ch = 0; ch < S_ / 128; ++ch) {
        const int c0 = ch * 128;
        // ---- stage this chunk: 128 steps x 80 f32 = 2560 float4, 40/lane ----
#pragma unroll
        for (int g = 0; g < 2; ++g) {
            float4 tmp[20];
#pragma unroll
            for (int k = 0; k < 20; ++k)
                tmp[k] = xwb4[(size_t)c0 * (G_ / 4) + l + 64 * (g * 20 + k)];
#pragma unroll
            for (int k = 0; k < 20; ++k)
                *(float4*)&stage[(l + 64 * (g * 20 + k)) * 4] = tmp[k];
        }
        __builtin_amdgcn_s_waitcnt(0);   // drain stage writes (single wave, no barrier)

        // ---- prime 4-deep ring from LDS rows 0..3 ----
#pragma unroll
        for (int u = 0; u < 4; ++u)
            if (ld) { ri[u] = stage[u * G_ + o1]; rf[u] = stage[u * G_ + o2]; }

        for (int T = 0; T < 124; T += 4) {
#pragma unroll
            for (int u = 0; u < 4; ++u) STEP(c0 + T + u, u, T + u + 4);
        }
#pragma unroll
        for (int u = 0; u < 4; ++u) STEP(c0 + 124 + u, u, -1);
    }

    // final head flush (output index S_-1) from final h
    {
        float hq[P_];
#pragma unroll
        for (int q = 0; q < P_; ++q) hq[q] = bcast(h, q);
        float pa = 0.f, pb = 0.f;
#pragma unroll
        for (int q = 0; q < P_ / 2; ++q) {
            pa += E[q] * hq[q];
            pb += E[q + 10] * hq[q + 10];
        }
        const float arg1 = pa + pb + hb;
        if (l == 23) sbuf[S_ - 1] = sigm_f(arg1);
        const float rv = fmaxf(arg1, 0.f);
        const float s0v = bcast(rv, 20);
        const float s1v = bcast(rv, 21);
        const float s2v = bcast(rv, 22);
        const float j = (float)(S_ - 1);
        float m = s0v * mu_prev + (s1v + s2v * (j + 1.f)) * invL;
        m = fmaxf(m, j * invL);
        if (l == 0) mbuf[S_ - 1] = m;
    }
    // coalesced flush
    __builtin_amdgcn_s_waitcnt(0);
#pragma unroll
    for (int i = 0; i < S_ / (64 * 4); ++i) {
        const int idx = (i * 64 + l) * 4;
        *(float4*)&mus[(size_t)b * S_ + idx] = *(const float4*)&mbuf[idx];
        *(float4*)&sigma[(size_t)b * S_ + idx] = *(const float4*)&sbuf[idx];
    }
}

// ---------------- K3: causal Gaussian attention, MFMA bf16 + LDS-staged B ----------------
__global__ __launch_bounds__(256, 2) void attn_kernel(const unsigned short* __restrict__ xT,
                                                      const float* __restrict__ mus,
                                                      const float* __restrict__ sigma,
                                                      const int* __restrict__ pad,
                                                      float* __restrict__ out) {
    __shared__ unsigned short xt[D_][40];   // 40 KB
    __shared__ float rsm[4][16];

    const int jt = (gridDim.x - 1) - blockIdx.x;
    const int b = blockIdx.y;
    const int tid = threadIdx.x;
    const int w = tid >> 6;
    const int l = tid & 63;
    const int lo = l & 15, hi = l >> 4;
    const int jw0 = jt * 64 + w * 16;
    const float invL = 1.f / (float)pad[b];

    const int jA = jw0 + lo;
    const float mu = mus[(size_t)b * S_ + jA];
    const float sg = sigma[(size_t)b * S_ + jA];
    const float nis = -1.f / (2.f * sg * sg + 0.001f);

    f32x4 acc[32];
#pragma unroll
    for (int dt = 0; dt < 32; ++dt) acc[dt] = (f32x4){0.f, 0.f, 0.f, 0.f};

    const unsigned short* xTb = xT + (size_t)b * D_ * S_;
    float rs = 0.f;
    const int kend = (jt + 1) * 64;

    for (int k0 = 0; k0 < kend; k0 += 32) {
        uint4 v[2][4];
#pragma unroll
        for (int rr = 0; rr < 2; ++rr) {
            const int d = tid + rr * 256;
            const uint4* src = (const uint4*)(xTb + (size_t)d * S_ + k0);
#pragma unroll
            for (int i = 0; i < 4; ++i) v[rr][i] = src[i];
        }
        __syncthreads();
#pragma unroll
        for (int rr = 0; rr < 2; ++rr) {
            const int d = tid + rr * 256;
#pragma unroll
            for (int i = 0; i < 4; ++i) *(uint4*)&xt[d][i * 8] = v[rr][i];
        }
        __syncthreads();

        short8v a;
#pragma unroll
        for (int e = 0; e < 8; ++e) {
            const int k = k0 + hi * 8 + e;
            const float dd = (float)k * invL - mu;
            const float wv = (k <= jA) ? __expf(dd * dd * nis) : 0.f;
            rs += wv;
            a[e] = (short)f2bf(wv);
        }
#pragma unroll
        for (int dt = 0; dt < 32; ++dt) {
            const short8v bf = *(const short8v*)&xt[dt * 16 + lo][hi * 8];
            acc[dt] = __builtin_amdgcn_mfma_f32_16x16x32_bf16(a, bf, acc[dt], 0, 0, 0);
        }
    }

    rs += __shfl_xor(rs, 16);
    rs += __shfl_xor(rs, 32);
    if (l < 16) rsm[w][l] = rs;
    __syncthreads();

#pragma unroll
    for (int r = 0; r < 4; ++r) {
        const int j = jw0 + hi * 4 + r;
        const float rcp = 1.f / fmaxf(rsm[w][hi * 4 + r], 1e-12f);
        float* ob = out + ((size_t)b * S_ + j) * D_ + lo;
#pragma unroll
        for (int dt = 0; dt < 32; ++dt) {
            ob[dt * 16] = acc[dt][r] * rcp;
        }
    }
}

extern "C" void kernel_launch(void* const* d_in, const int* in_sizes, int n_in,
                              void* d_out, int out_size, void* d_ws, size_t ws_size,
                              hipStream_t stream) {
    const float* x     = (const float*)d_in[0];
    const int*   pad   = (const int*)d_in[1];
    const float* W_ih  = (const float*)d_in[2];
    const float* W_hh  = (const float*)d_in[3];
    const float* b_ih  = (const float*)d_in[4];
    const float* b_hh  = (const float*)d_in[5];
    const float* W_mu  = (const float*)d_in[6];
    const float* b_mu  = (const float*)d_in[7];
    const float* W_sig = (const float*)d_in[8];
    const float* b_sig = (const float*)d_in[9];
    float* out = (float*)d_out;

    float* xw    = (float*)d_ws;
    float* mus   = xw + (size_t)B_ * S_ * G_;
    float* sigma = mus + (size_t)B_ * S_;
    unsigned short* xT = (unsigned short*)(sigma + (size_t)B_ * S_);

    xw_kernel<<<(B_ * S_) / 64, 256, 0, stream>>>(x, W_ih, b_ih, b_hh, xw);
    conv_kernel<<<dim3(S_ / 64, D_ / 64, B_), 256, 0, stream>>>(x, xT);
    lstm_kernel<<<B_, 64, 0, stream>>>(xw, W_hh, W_mu, b_mu, W_sig, b_sig, pad, mus, sigma);
    attn_kernel<<<dim3(S_ / 64, B_), 256, 0, stream>>>(xT, mus, sigma, pad, out);
}

// Round 9
// 664.024 us; speedup vs baseline: 1.2789x; 1.2789x over previous
//
#include <hip/hip_runtime.h>
#include <hip/hip_bf16.h>

#define B_ 32
#define S_ 1024
#define D_ 512
#define P_ 20
#define G_ 80   // 4*P

typedef __attribute__((ext_vector_type(8))) short short8v;
typedef __attribute__((ext_vector_type(4))) float f32x4;

__device__ __forceinline__ float sigm_f(float x) { return 1.f / (1.f + __expf(-x)); }
__device__ __forceinline__ float tanh_f(float x) { return 1.f - 2.f / (__expf(2.f * x) + 1.f); }
__device__ __forceinline__ unsigned short f2bf(float f) {
    unsigned int u = __float_as_uint(f);
    u += 0x7FFF + ((u >> 16) & 1);   // RNE; inputs are finite
    return (unsigned short)(u >> 16);
}
__device__ __forceinline__ float bcast(float v, int lane) {
    return __uint_as_float(__builtin_amdgcn_readlane(__float_as_uint(v), lane));
}
__device__ __forceinline__ short8v cvt8(float4 p, float4 q) {
    union { __hip_bfloat162 h2[4]; short8v s; } u;
    u.h2[0] = __float22bfloat162_rn(float2{p.x, p.y});
    u.h2[1] = __float22bfloat162_rn(float2{p.z, p.w});
    u.h2[2] = __float22bfloat162_rn(float2{q.x, q.y});
    u.h2[3] = __float22bfloat162_rn(float2{q.z, q.w});
    return u.s;
}

// ---------------- K1: xw = x @ W_ih^T + b_ih + b_hh  via MFMA bf16 ----------------
__global__ __launch_bounds__(256) void xw_kernel(const float* __restrict__ x,
                                                 const float* __restrict__ W_ih,
                                                 const float* __restrict__ b_ih,
                                                 const float* __restrict__ b_hh,
                                                 float* __restrict__ xw) {
    const int tid = threadIdx.x;
    const int w = tid >> 6, l = tid & 63;
    const int lo = l & 15, hi = l >> 4;
    const int m0 = blockIdx.x * 64 + w * 16;

    f32x4 acc[5];
#pragma unroll
    for (int n = 0; n < 5; ++n) acc[n] = (f32x4){0.f, 0.f, 0.f, 0.f};

    const float* xrow = x + (size_t)(m0 + lo) * D_ + hi * 8;
#pragma unroll 4
    for (int k0 = 0; k0 < D_; k0 += 32) {
        const float4 a0 = *(const float4*)(xrow + k0);
        const float4 a1 = *(const float4*)(xrow + k0 + 4);
        const short8v a = cvt8(a0, a1);
#pragma unroll
        for (int n = 0; n < 5; ++n) {
            const float* wr = W_ih + (size_t)(n * 16 + lo) * D_ + k0 + hi * 8;
            const float4 b0 = *(const float4*)(wr);
            const float4 b1 = *(const float4*)(wr + 4);
            const short8v bf = cvt8(b0, b1);
            acc[n] = __builtin_amdgcn_mfma_f32_16x16x32_bf16(a, bf, acc[n], 0, 0, 0);
        }
    }
#pragma unroll
    for (int n = 0; n < 5; ++n) {
        const int g = n * 16 + lo;
        const float bias = b_ih[g] + b_hh[g];
#pragma unroll
        for (int r = 0; r < 4; ++r) {
            const int m = m0 + hi * 4 + r;
            xw[(size_t)m * G_ + g] = acc[n][r] + bias;
        }
    }
}

// ---------------- K1b: x -> XT2[b][kt][d][ks] bf16 (k-tiled: each 32k x 512d tile contiguous) ----------------
__global__ __launch_bounds__(256) void conv_kernel(const float* __restrict__ x,
                                                   unsigned short* __restrict__ xT2) {
    __shared__ unsigned short tile[64][80];
    const int b = blockIdx.z;
    const int s0 = blockIdx.x * 64;
    const int d0 = blockIdx.y * 64;
    const int t = threadIdx.x;
    const int r = t >> 2;
    const int c0 = (t & 3) * 16;

    const float4* src = (const float4*)(x + ((size_t)(b * S_ + s0 + r)) * D_ + d0 + c0);
    float4 v0 = src[0], v1 = src[1], v2 = src[2], v3 = src[3];
    float vv[16] = {v0.x, v0.y, v0.z, v0.w, v1.x, v1.y, v1.z, v1.w,
                    v2.x, v2.y, v2.z, v2.w, v3.x, v3.y, v3.z, v3.w};
#pragma unroll
    for (int e = 0; e < 16; ++e) tile[c0 + e][r] = f2bf(vv[e]);
    __syncthreads();

    const int dr = t >> 2;           // d row 0..63
    const int sc = (t & 3) * 16;     // s col base 0/16/32/48
    const unsigned short* tr = &tile[dr][sc];
    uint4 w0 = *(const uint4*)(tr);
    uint4 w1 = *(const uint4*)(tr + 8);
    const int st = (s0 + sc) >> 5;   // k-tile
    const int ks = (s0 + sc) & 31;   // 0 or 16
    uint4* dst = (uint4*)(xT2 + ((size_t)(b * 32 + st) * D_ + d0 + dr) * 32 + ks);
    dst[0] = w0;
    dst[1] = w1;
}

// ---------------- K2: split-gate wave-synchronous LSTM (R5-exact, best measured) ----------------
__global__ __launch_bounds__(64) void lstm_kernel(const float* __restrict__ xw,
                                                  const float* __restrict__ W_hh,
                                                  const float* __restrict__ W_mu,
                                                  const float* __restrict__ b_mu,
                                                  const float* __restrict__ W_sig,
                                                  const float* __restrict__ b_sig,
                                                  const int* __restrict__ pad,
                                                  float* __restrict__ mus,
                                                  float* __restrict__ sigma) {
    const int b = blockIdx.x;
    const int l = threadIdx.x;
    __shared__ float mbuf[S_];
    __shared__ float sbuf[S_];

    float E[P_], F[P_];
#pragma unroll
    for (int q = 0; q < P_; ++q) { E[q] = 0.f; F[q] = 0.f; }
    if (l < P_) {
#pragma unroll
        for (int q = 0; q < P_; ++q) {
            E[q] = W_hh[(0 * P_ + l) * P_ + q];   // i row
            F[q] = W_hh[(1 * P_ + l) * P_ + q];   // f row
        }
    } else if (l < 23) {
#pragma unroll
        for (int q = 0; q < P_; ++q) E[q] = W_mu[(l - 20) * P_ + q];
    } else if (l == 23) {
#pragma unroll
        for (int q = 0; q < P_; ++q) E[q] = W_sig[q];
    } else if (l >= 32 && l < 32 + P_) {
        const int p = l - 32;
#pragma unroll
        for (int q = 0; q < P_; ++q) {
            E[q] = W_hh[(2 * P_ + p) * P_ + q];   // g row
            F[q] = W_hh[(3 * P_ + p) * P_ + q];   // o row
        }
    }

    const float invL = 1.f / (float)pad[b];
    const float hb = (l >= 20 && l < 23) ? b_mu[l - 20] : (l == 23 ? b_sig[0] : 0.f);
    const float ka = (l >= 32) ? 2.f : 1.f;
    const float Ka = (l >= 32) ? 2.f : 1.f;
    const float Kb = (l >= 32) ? -1.f : 0.f;
    const bool ld = (l < P_) || (l >= 32 && l < 32 + P_);
    const int o1 = (l < 32) ? l : (2 * P_ + (l - 32));          // i or g column
    const int o2 = (l < 32) ? (P_ + l) : (3 * P_ + (l - 32));   // f or o column

    float h = 0.f, c = 0.f, mu_prev = 0.f;
    const float* xwb = xw + (size_t)b * S_ * G_;

    // 8-deep prefetch ring
    float ri[8], rf[8];
#pragma unroll
    for (int u = 0; u < 8; ++u) {
        ri[u] = 0.f; rf[u] = 0.f;
        if (ld) {
            const float* r = xwb + (size_t)u * G_;
            ri[u] = r[o1]; rf[u] = r[o2];
        }
    }

    for (int T = 0; T < S_; T += 8) {
#pragma unroll
        for (int u = 0; u < 8; ++u) {
            const int t = T + u;
            float hq[P_];
#pragma unroll
            for (int q = 0; q < P_; ++q) hq[q] = bcast(h, q);

            float pa = 0.f, pb = 0.f, qa = 0.f, qb = 0.f;
#pragma unroll
            for (int q = 0; q < P_ / 2; ++q) {
                pa += E[q] * hq[q];            qa += F[q] * hq[q];
                pb += E[q + 10] * hq[q + 10];  qb += F[q + 10] * hq[q + 10];
            }
            const float arg1 = pa + pb + ri[u] + hb;
            const float arg2 = qa + qb + rf[u];

            const float s1 = sigm_f(ka * arg1);
            const float a1 = Ka * s1 + Kb;          // sigm (lo) / tanh (hi)
            const float a2 = sigm_f(arg2);
            const float rv = fmaxf(arg1, 0.f);      // relu for mu head lanes

            const float gx = __shfl_xor(a1, 32);    // partner's a1
            const float ox = __shfl_xor(a2, 32);    // partner's a2

            c = a2 * c + a1 * gx;
            h = ox * tanh_f(c);

            if (ld && t + 8 < S_) {
                const float* r = xwb + (size_t)(t + 8) * G_;
                ri[u] = r[o1]; rf[u] = r[o2];
            }
            if (t > 0) {
                if (l == 23) sbuf[t - 1] = s1;
                const float s0v = bcast(rv, 20);
                const float s1v = bcast(rv, 21);
                const float s2v = bcast(rv, 22);
                if (l == 0) {
                    const float j = (float)(t - 1);
                    float m = s0v * mu_prev + (s1v + s2v * (j + 1.f)) * invL;
                    m = fmaxf(m, j * invL);
                    mu_prev = m;
                    mbuf[t - 1] = m;
                }
            }
        }
    }
    // final head flush (output index S_-1) from final h
    {
        float hq[P_];
#pragma unroll
        for (int q = 0; q < P_; ++q) hq[q] = bcast(h, q);
        float pa = 0.f, pb = 0.f;
#pragma unroll
        for (int q = 0; q < P_ / 2; ++q) {
            pa += E[q] * hq[q];
            pb += E[q + 10] * hq[q + 10];
        }
        const float arg1 = pa + pb + hb;
        if (l == 23) sbuf[S_ - 1] = sigm_f(arg1);
        const float rv = fmaxf(arg1, 0.f);
        const float s0v = bcast(rv, 20);
        const float s1v = bcast(rv, 21);
        const float s2v = bcast(rv, 22);
        if (l == 0) {
            const float j = (float)(S_ - 1);
            float m = s0v * mu_prev + (s1v + s2v * (j + 1.f)) * invL;
            m = fmaxf(m, j * invL);
            mbuf[S_ - 1] = m;
        }
    }
    __builtin_amdgcn_s_waitcnt(0);
#pragma unroll
    for (int i = 0; i < S_ / (64 * 4); ++i) {
        const int idx = (i * 64 + l) * 4;
        *(float4*)&mus[(size_t)b * S_ + idx] = *(const float4*)&mbuf[idx];
        *(float4*)&sigma[(size_t)b * S_ + idx] = *(const float4*)&sbuf[idx];
    }
}

// ---------------- K3: causal Gaussian attention, MFMA bf16, contiguous tile staging ----------------
__global__ __launch_bounds__(256, 2) void attn_kernel(const unsigned short* __restrict__ xT2,
                                                      const float* __restrict__ mus,
                                                      const float* __restrict__ sigma,
                                                      const int* __restrict__ pad,
                                                      float* __restrict__ out) {
    __shared__ unsigned short xt[D_][40];   // 40 KB
    __shared__ float rsm[4][16];

    const int jt = (gridDim.x - 1) - blockIdx.x;  // heavy tiles dispatch first
    const int b = blockIdx.y;
    const int tid = threadIdx.x;
    const int w = tid >> 6;
    const int l = tid & 63;
    const int lo = l & 15, hi = l >> 4;
    const int jw0 = jt * 64 + w * 16;
    const float invL = 1.f / (float)pad[b];

    const int jA = jw0 + lo;
    const float mu = mus[(size_t)b * S_ + jA];
    const float sg = sigma[(size_t)b * S_ + jA];
    const float nis = -1.f / (2.f * sg * sg + 0.001f);

    f32x4 acc[32];
#pragma unroll
    for (int dt = 0; dt < 32; ++dt) acc[dt] = (f32x4){0.f, 0.f, 0.f, 0.f};

    float rs = 0.f;
    const int ktend = (jt + 1) * 2;   // k-tiles of 32

    for (int kt = 0; kt < ktend; ++kt) {
        const int k0 = kt * 32;
        // contiguous 32KB tile: XT2[b][kt][d][ks]
        const uint4* src = (const uint4*)(xT2 + ((size_t)(b * 32 + kt)) * D_ * 32);
        uint4 v[8];
#pragma unroll
        for (int i = 0; i < 8; ++i) v[i] = src[i * 256 + tid];   // coalesced 1KB/wave/instr
        __syncthreads();   // previous iteration's frag reads complete
#pragma unroll
        for (int i = 0; i < 8; ++i) {
            const int j = i * 256 + tid;                          // 16B unit index
            *(uint4*)&xt[j >> 2][(j & 3) * 8] = v[i];
        }
        __syncthreads();   // tile visible

        // A fragment (Gaussian weights) + partial row-sum
        short8v a;
#pragma unroll
        for (int e = 0; e < 8; ++e) {
            const int k = k0 + hi * 8 + e;
            const float dd = (float)k * invL - mu;
            const float wv = (k <= jA) ? __expf(dd * dd * nis) : 0.f;
            rs += wv;
            a[e] = (short)f2bf(wv);
        }
#pragma unroll
        for (int dt = 0; dt < 32; ++dt) {
            const short8v bf = *(const short8v*)&xt[dt * 16 + lo][hi * 8];
            acc[dt] = __builtin_amdgcn_mfma_f32_16x16x32_bf16(a, bf, acc[dt], 0, 0, 0);
        }
    }

    rs += __shfl_xor(rs, 16);
    rs += __shfl_xor(rs, 32);
    if (l < 16) rsm[w][l] = rs;
    __syncthreads();

#pragma unroll
    for (int r = 0; r < 4; ++r) {
        const int j = jw0 + hi * 4 + r;
        const float rcp = 1.f / fmaxf(rsm[w][hi * 4 + r], 1e-12f);
        float* ob = out + ((size_t)b * S_ + j) * D_ + lo;
#pragma unroll
        for (int dt = 0; dt < 32; ++dt) {
            ob[dt * 16] = acc[dt][r] * rcp;
        }
    }
}

extern "C" void kernel_launch(void* const* d_in, const int* in_sizes, int n_in,
                              void* d_out, int out_size, void* d_ws, size_t ws_size,
                              hipStream_t stream) {
    const float* x     = (const float*)d_in[0];
    const int*   pad   = (const int*)d_in[1];
    const float* W_ih  = (const float*)d_in[2];
    const float* W_hh  = (const float*)d_in[3];
    const float* b_ih  = (const float*)d_in[4];
    const float* b_hh  = (const float*)d_in[5];
    const float* W_mu  = (const float*)d_in[6];
    const float* b_mu  = (const float*)d_in[7];
    const float* W_sig = (const float*)d_in[8];
    const float* b_sig = (const float*)d_in[9];
    float* out = (float*)d_out;

    float* xw    = (float*)d_ws;
    float* mus   = xw + (size_t)B_ * S_ * G_;
    float* sigma = mus + (size_t)B_ * S_;
    unsigned short* xT2 = (unsigned short*)(sigma + (size_t)B_ * S_);

    xw_kernel<<<(B_ * S_) / 64, 256, 0, stream>>>(x, W_ih, b_ih, b_hh, xw);
    conv_kernel<<<dim3(S_ / 64, D_ / 64, B_), 256, 0, stream>>>(x, xT2);
    lstm_kernel<<<B_, 64, 0, stream>>>(xw, W_hh, W_mu, b_mu, W_sig, b_sig, pad, mus, sigma);
    attn_kernel<<<dim3(S_ / 64, B_), 256, 0, stream>>>(xT2, mus, sigma, pad, out);
}